// Round 11
// baseline (178.089 us; speedup 1.0000x reference)
//
#include <hip/hip_runtime.h>

#define IMG_W 2048
#define NUM_NODES 255
#define NLEAF 128
#define DEPTH 7
#define RS 68        // padded row stride (floats); 16B-chunk bank-group = (row+q)%8 balanced
#define NPATCH 128   // patches per block

// DPP xor-butterfly add over 16-lane groups (VALU pipe). Butterfly partners add
// identical pairs -> all 16 lanes end bit-identical.
template<int CTRL>
__device__ __forceinline__ float dpp_add(float x) {
    int v = __builtin_amdgcn_update_dpp(0, __float_as_int(x), CTRL, 0xF, 0xF, true);
    return x + __int_as_float(v);
}
__device__ __forceinline__ float group16_sum(float x) {
    x = dpp_add<0xB1>(x);   // quad_perm [1,0,3,2]  : xor 1
    x = dpp_add<0x4E>(x);   // quad_perm [2,3,0,1]  : xor 2
    x = dpp_add<0x141>(x);  // row_half_mirror      : xor 7
    x = dpp_add<0x128>(x);  // row_ror:8            : xor 8
    return x;
}

// ---- K1: interleaved descent + counting-sort + dense segmented accumulate ---
// 512 blocks x 512 thr, ~72 KB LDS -> 2 blocks/CU (16 waves). ZERO ds_add_f32.
__global__ __launch_bounds__(512, 4) void fusedK(const float* __restrict__ img,
                                                 const float* __restrict__ nodes,
                                                 float* __restrict__ leaf_out,
                                                 float* __restrict__ S,
                                                 unsigned* __restrict__ cnt)
{
    __shared__ float nds[NUM_NODES * RS];   // 69360 B; XN (128*RS=8704 fl) overlays after descent
    __shared__ int   Lbuf[NPATCH];
    __shared__ int   pos[NLEAF + 1];        // prefix-scan of per-leaf counts
    __shared__ int   curp[NLEAF];           // scatter cursors
    __shared__ int   sortedIdx[NPATCH];     // patch indices sorted by leaf
    __shared__ int   cntl[NLEAF];
    float* XN = nds;                        // overlay (phase 2)

    const int t = threadIdx.x;
    const int b = blockIdx.x;
    const int g = t >> 4;          // patch-group 0..31
    const int q = t & 15;          // quad within patch
    const int q4 = q * 4;

    if (t < NLEAF) cntl[t] = 0;

    // fill node table (padded rows)
    const float4* ng = (const float4*)nodes;
    for (int i = t; i < NUM_NODES * 16; i += 512) {
        *(float4*)&nds[(i >> 4) * RS + (i & 15) * 4] = ng[i];
    }

    // prefetch 4 chunks' patch quads (element e=4q+j -> pixel (q>>1, (q&1)*4+j))
    float4 xv0, xv1, xv2, xv3;
    {
        const int roff = (q >> 1), coff = (q & 1) * 4;
        int p = b * NPATCH + g;
        xv0 = *(const float4*)(img + (size_t)((p >> 8) * 8 + roff) * IMG_W + (p & 255) * 8 + coff);
        p += 32;
        xv1 = *(const float4*)(img + (size_t)((p >> 8) * 8 + roff) * IMG_W + (p & 255) * 8 + coff);
        p += 32;
        xv2 = *(const float4*)(img + (size_t)((p >> 8) * 8 + roff) * IMG_W + (p & 255) * 8 + coff);
        p += 32;
        xv3 = *(const float4*)(img + (size_t)((p >> 8) * 8 + roff) * IMG_W + (p & 255) * 8 + coff);
    }
    __syncthreads();

    // 4-way interleaved descent (R10 structure: one read batch + one wait per level)
    int cur0 = 0, cur1 = 0, cur2 = 0, cur3 = 0;
    #pragma unroll
    for (int lvl = 0; lvl < DEPTH; ++lvl) {
        const int ca = 2 * cur0 + 1, cb = 2 * cur1 + 1, cc = 2 * cur2 + 1, cd = 2 * cur3 + 1;
        const float* pa = &nds[ca * RS + q4];
        const float* pb = &nds[cb * RS + q4];
        const float* pc = &nds[cc * RS + q4];
        const float* pd = &nds[cd * RS + q4];
        const float4 A0 = *(const float4*)(pa);
        const float4 B0 = *(const float4*)(pa + RS);
        const float4 A1 = *(const float4*)(pb);
        const float4 B1 = *(const float4*)(pb + RS);
        const float4 A2 = *(const float4*)(pc);
        const float4 B2 = *(const float4*)(pc + RS);
        const float4 A3 = *(const float4*)(pd);
        const float4 B3 = *(const float4*)(pd + RS);

        float d, s0, s1;
        s0 = 0.f; s1 = 0.f;
        d = A0.x - xv0.x; s0 = fmaf(d, d, s0);  d = B0.x - xv0.x; s1 = fmaf(d, d, s1);
        d = A0.y - xv0.y; s0 = fmaf(d, d, s0);  d = B0.y - xv0.y; s1 = fmaf(d, d, s1);
        d = A0.z - xv0.z; s0 = fmaf(d, d, s0);  d = B0.z - xv0.z; s1 = fmaf(d, d, s1);
        d = A0.w - xv0.w; s0 = fmaf(d, d, s0);  d = B0.w - xv0.w; s1 = fmaf(d, d, s1);
        cur0 = (group16_sum(s1 - s0) < 0.0f) ? (ca + 1) : ca;   // d1<d0 picks c1 (strict)
        s0 = 0.f; s1 = 0.f;
        d = A1.x - xv1.x; s0 = fmaf(d, d, s0);  d = B1.x - xv1.x; s1 = fmaf(d, d, s1);
        d = A1.y - xv1.y; s0 = fmaf(d, d, s0);  d = B1.y - xv1.y; s1 = fmaf(d, d, s1);
        d = A1.z - xv1.z; s0 = fmaf(d, d, s0);  d = B1.z - xv1.z; s1 = fmaf(d, d, s1);
        d = A1.w - xv1.w; s0 = fmaf(d, d, s0);  d = B1.w - xv1.w; s1 = fmaf(d, d, s1);
        cur1 = (group16_sum(s1 - s0) < 0.0f) ? (cb + 1) : cb;
        s0 = 0.f; s1 = 0.f;
        d = A2.x - xv2.x; s0 = fmaf(d, d, s0);  d = B2.x - xv2.x; s1 = fmaf(d, d, s1);
        d = A2.y - xv2.y; s0 = fmaf(d, d, s0);  d = B2.y - xv2.y; s1 = fmaf(d, d, s1);
        d = A2.z - xv2.z; s0 = fmaf(d, d, s0);  d = B2.z - xv2.z; s1 = fmaf(d, d, s1);
        d = A2.w - xv2.w; s0 = fmaf(d, d, s0);  d = B2.w - xv2.w; s1 = fmaf(d, d, s1);
        cur2 = (group16_sum(s1 - s0) < 0.0f) ? (cc + 1) : cc;
        s0 = 0.f; s1 = 0.f;
        d = A3.x - xv3.x; s0 = fmaf(d, d, s0);  d = B3.x - xv3.x; s1 = fmaf(d, d, s1);
        d = A3.y - xv3.y; s0 = fmaf(d, d, s0);  d = B3.y - xv3.y; s1 = fmaf(d, d, s1);
        d = A3.z - xv3.z; s0 = fmaf(d, d, s0);  d = B3.z - xv3.z; s1 = fmaf(d, d, s1);
        d = A3.w - xv3.w; s0 = fmaf(d, d, s0);  d = B3.w - xv3.w; s1 = fmaf(d, d, s1);
        cur3 = (group16_sum(s1 - s0) < 0.0f) ? (cd + 1) : cd;
    }

    if (q == 0) {
        leaf_out[b * NPATCH + g]      = (float)cur0;
        leaf_out[b * NPATCH + 32 + g] = (float)cur1;
        leaf_out[b * NPATCH + 64 + g] = (float)cur2;
        leaf_out[b * NPATCH + 96 + g] = (float)cur3;
        Lbuf[g]      = cur0 - 127;
        Lbuf[32 + g] = cur1 - 127;
        Lbuf[64 + g] = cur2 - 127;
        Lbuf[96 + g] = cur3 - 127;
        atomicAdd(&cntl[cur0 - 127], 1);   // int adds, 4 active lanes/wave: cheap
        atomicAdd(&cntl[cur1 - 127], 1);
        atomicAdd(&cntl[cur2 - 127], 1);
        atomicAdd(&cntl[cur3 - 127], 1);
    }
    __syncthreads();                       // descents done reading nds; cntl final

    // stage patches into XN (overlay; plain b128 writes)
    *(float4*)&XN[(g)      * RS + q4] = xv0;
    *(float4*)&XN[(32 + g) * RS + q4] = xv1;
    *(float4*)&XN[(64 + g) * RS + q4] = xv2;
    *(float4*)&XN[(96 + g) * RS + q4] = xv3;

    // block-wide Hillis-Steele inclusive scan: pos[L] = #patches with leaf < L
    if (t == 0) pos[0] = 0;
    if (t < NLEAF) pos[t + 1] = cntl[t];
    __syncthreads();
    for (int st = 1; st <= NLEAF; st <<= 1) {
        int v = 0;
        if (t <= NLEAF && t >= st) v = pos[t - st];
        __syncthreads();
        if (t <= NLEAF && t >= st) pos[t] += v;
        __syncthreads();
    }
    if (t < NLEAF) curp[t] = pos[t];
    __syncthreads();

    // scatter patch indices by leaf (int cursor bumps; 128 total per block)
    if (q == 0) {
        int i0 = atomicAdd(&curp[Lbuf[g]], 1);       sortedIdx[i0] = g;
        int i1 = atomicAdd(&curp[Lbuf[32 + g]], 1);  sortedIdx[i1] = 32 + g;
        int i2 = atomicAdd(&curp[Lbuf[64 + g]], 1);  sortedIdx[i2] = 64 + g;
        int i3 = atomicAdd(&curp[Lbuf[96 + g]], 1);  sortedIdx[i3] = 96 + g;
    }
    __syncthreads();

    // dense segmented sweep: wave w owns leaves 16w..16w+15; lane k = element k.
    // sortedIdx read = same-address broadcast (free); XN read banks (4p+k)%32 ->
    // 2 lanes/bank (free). Single scalar accumulator -> no spill risk.
    const int w = t >> 6, k = t & 63;
    #pragma unroll
    for (int r = 0; r < 16; ++r) {
        const int L = w * 16 + r;
        const int s = pos[L], e = pos[L + 1];      // wave-uniform broadcast
        if (e > s) {
            float acc = 0.0f;
            for (int i = s; i < e; ++i) {
                acc += XN[sortedIdx[i] * RS + k];
            }
            atomicAdd(&S[L * 64 + k], acc);        // lane-distinct global atomics
            if (k == 0) atomicAdd(&cnt[L], (unsigned)(e - s));
        }
    }
}

// ---------------- K2: node update (254x64x128 contraction) -------------------
__global__ __launch_bounds__(256) void updateK(const float* __restrict__ nodes,
                                               const float* __restrict__ S,
                                               const unsigned* __restrict__ cnt,
                                               float* __restrict__ out)
{
    const int gid = blockIdx.x * 256 + threadIdx.x;
    if (gid >= NUM_NODES * 64) return;
    const int n = gid >> 6, k = gid & 63;
    const float nd = nodes[gid];
    if (n == 0) { out[gid] = nd; return; }

    const int pos = n + 1;                 // 1-based heap index
    const int Ln = 31 - __clz(pos);        // node level, 1..7
    float su = 0.f, sc = 0.f;
    #pragma unroll 8
    for (int L = 0; L < NLEAF; ++L) {
        const int a = (128 + L) >> (7 - Ln);   // leaf's ancestor at level Ln
        const int x = pos ^ a;
        const int state = (x == 0) ? Ln : (Ln - (31 - __clz(x)) - 1);
        const float lr = 0.3f * ((float)(1 << state) * (1.0f / 128.0f));
        su = fmaf(lr, S[L * 64 + k], su);
        sc = fmaf(lr, (float)cnt[L], sc);
    }
    const float invP = 1.0f / 65536.0f;
    out[gid] = nd + su * invP - (sc * invP) * nd;
}

extern "C" void kernel_launch(void* const* d_in, const int* in_sizes, int n_in,
                              void* d_out, int out_size, void* d_ws, size_t ws_size,
                              hipStream_t stream)
{
    const float* img   = (const float*)d_in[0];   // 2048*2048 f32
    const float* nodes = (const float*)d_in[1];   // 255*64 f32

    float* out_nodes = (float*)d_out;                 // 255*64
    float* out_leaf  = out_nodes + NUM_NODES * 64;    // 65536 (leaf index as f32)

    float*    S   = (float*)d_ws;                     // 128*64 f32
    unsigned* cnt = (unsigned*)(S + NLEAF * 64);      // 128 u32

    hipMemsetAsync(d_ws, 0, (NLEAF * 64) * sizeof(float) + NLEAF * sizeof(unsigned), stream);
    fusedK<<<512, 512, 0, stream>>>(img, nodes, out_leaf, S, cnt);
    updateK<<<64, 256, 0, stream>>>(nodes, S, cnt, out_nodes);
}

// Round 12
// 110.119 us; speedup vs baseline: 1.6172x; 1.6172x over previous
//
#include <hip/hip_runtime.h>

#define IMG_W 2048
#define NUM_NODES 255
#define NLEAF 128
#define DEPTH 7
#define RS 68   // padded LDS row stride (floats); 16B-chunk bank-group = (row+q)%8 -> balanced

// DPP xor-butterfly add over 16-lane groups (VALU pipe). Butterfly partners add
// identical pairs -> all 16 lanes end bit-identical.
template<int CTRL>
__device__ __forceinline__ float dpp_add(float x) {
    int v = __builtin_amdgcn_update_dpp(0, __float_as_int(x), CTRL, 0xF, 0xF, true);
    return x + __int_as_float(v);
}
__device__ __forceinline__ float group16_sum(float x) {
    x = dpp_add<0xB1>(x);   // quad_perm [1,0,3,2]  : xor 1
    x = dpp_add<0x4E>(x);   // quad_perm [2,3,0,1]  : xor 2
    x = dpp_add<0x141>(x);  // row_half_mirror      : xor 7
    x = dpp_add<0x128>(x);  // row_ror:8            : xor 8
    return x;
}

// ---- K0: LLC pre-touch (image + nodes) + S/cnt zero-init --------------------
// Streams 16.8 MB of image into LLC with maximally-coalesced dwordx4 reads so
// fusedK's reads hit cache. Absorbs any residual HBM contention from the
// harness's 262 MB ws re-poison. Also zeroes S/cnt (replaces memset dispatch).
__global__ __launch_bounds__(256) void preloadK(const float* __restrict__ img,
                                                const float* __restrict__ nodes,
                                                float* __restrict__ S,
                                                unsigned* __restrict__ cnt,
                                                float* __restrict__ sink)
{
    const int t = threadIdx.x;
    const int b = blockIdx.x;
    const int gid = b * 256 + t;

    if (gid < NLEAF * 64) S[gid] = 0.0f;
    if (gid < NLEAF) cnt[gid] = 0u;

    // image: 2048*2048 floats = 1,048,576 float4; 2048 blocks x 256 thr x 2 each
    const float4* im4 = (const float4*)img;
    float4 a = im4[gid];
    float4 c = im4[524288 + gid];
    float acc = a.x + a.y + a.z + a.w + c.x + c.y + c.z + c.w;
    // nodes: 16320 floats = 4080 float4 (first 16 blocks)
    if (gid < 4080) {
        const float4* nd4 = (const float4*)nodes;
        float4 n = nd4[gid];
        acc += n.x + n.y + n.z + n.w;
    }
    if (acc == -1234567.0f) sink[b] = acc;   // un-DCE-able, never taken (inputs in [0,1))
}

// ---- K1: 4-way interleaved descent (16 lanes/patch) + LDS-atomic accumulate --
// EXACTLY the R10 structure (42.3 us baseline, VGPR 52): one read batch + one
// wait per level, quad ds_add accumulate, skip-zero global flush.
__global__ __launch_bounds__(1024, 4) void fusedK(const float* __restrict__ img,
                                                  const float* __restrict__ nodes,
                                                  float* __restrict__ leaf_out,
                                                  float* __restrict__ S,
                                                  unsigned* __restrict__ cnt)
{
    __shared__ float nds[NUM_NODES * RS];   // 69360 B
    __shared__ float Sl[NLEAF * RS];        // 34816 B
    __shared__ unsigned cntl[NLEAF];

    const int t = threadIdx.x;
    const int b = blockIdx.x;
    const int g = t >> 4;          // patch-group 0..63
    const int q = t & 15;          // quad within patch (elements 4q..4q+3)
    const int q4 = q * 4;

    for (int i = t; i < NLEAF * RS; i += 1024) Sl[i] = 0.0f;
    if (t < NLEAF) cntl[t] = 0u;

    // fill node table (padded rows)
    const float4* ng = (const float4*)nodes;
    for (int i = t; i < NUM_NODES * 16; i += 1024) {
        *(float4*)&nds[(i >> 4) * RS + (i & 15) * 4] = ng[i];
    }

    // prefetch 4 chunks' patch quads (element e=4q+j -> pixel (q>>1, (q&1)*4+j))
    float4 xv0, xv1, xv2, xv3;
    {
        const int roff = (q >> 1), coff = (q & 1) * 4;
        int p = b * 256 + g;
        xv0 = *(const float4*)(img + (size_t)((p >> 8) * 8 + roff) * IMG_W + (p & 255) * 8 + coff);
        p += 64;
        xv1 = *(const float4*)(img + (size_t)((p >> 8) * 8 + roff) * IMG_W + (p & 255) * 8 + coff);
        p += 64;
        xv2 = *(const float4*)(img + (size_t)((p >> 8) * 8 + roff) * IMG_W + (p & 255) * 8 + coff);
        p += 64;
        xv3 = *(const float4*)(img + (size_t)((p >> 8) * 8 + roff) * IMG_W + (p & 255) * 8 + coff);
    }
    __syncthreads();

    // 4 interleaved descents
    int cur0 = 0, cur1 = 0, cur2 = 0, cur3 = 0;
    #pragma unroll
    for (int lvl = 0; lvl < DEPTH; ++lvl) {
        const int ca = 2 * cur0 + 1, cb = 2 * cur1 + 1, cc = 2 * cur2 + 1, cd = 2 * cur3 + 1;
        const float* pa = &nds[ca * RS + q4];
        const float* pb = &nds[cb * RS + q4];
        const float* pc = &nds[cc * RS + q4];
        const float* pd = &nds[cd * RS + q4];
        const float4 A0 = *(const float4*)(pa);
        const float4 B0 = *(const float4*)(pa + RS);
        const float4 A1 = *(const float4*)(pb);
        const float4 B1 = *(const float4*)(pb + RS);
        const float4 A2 = *(const float4*)(pc);
        const float4 B2 = *(const float4*)(pc + RS);
        const float4 A3 = *(const float4*)(pd);
        const float4 B3 = *(const float4*)(pd + RS);

        float d, s0, s1;
        s0 = 0.f; s1 = 0.f;
        d = A0.x - xv0.x; s0 = fmaf(d, d, s0);  d = B0.x - xv0.x; s1 = fmaf(d, d, s1);
        d = A0.y - xv0.y; s0 = fmaf(d, d, s0);  d = B0.y - xv0.y; s1 = fmaf(d, d, s1);
        d = A0.z - xv0.z; s0 = fmaf(d, d, s0);  d = B0.z - xv0.z; s1 = fmaf(d, d, s1);
        d = A0.w - xv0.w; s0 = fmaf(d, d, s0);  d = B0.w - xv0.w; s1 = fmaf(d, d, s1);
        cur0 = (group16_sum(s1 - s0) < 0.0f) ? (ca + 1) : ca;   // d1<d0 picks c1 (strict)
        s0 = 0.f; s1 = 0.f;
        d = A1.x - xv1.x; s0 = fmaf(d, d, s0);  d = B1.x - xv1.x; s1 = fmaf(d, d, s1);
        d = A1.y - xv1.y; s0 = fmaf(d, d, s0);  d = B1.y - xv1.y; s1 = fmaf(d, d, s1);
        d = A1.z - xv1.z; s0 = fmaf(d, d, s0);  d = B1.z - xv1.z; s1 = fmaf(d, d, s1);
        d = A1.w - xv1.w; s0 = fmaf(d, d, s0);  d = B1.w - xv1.w; s1 = fmaf(d, d, s1);
        cur1 = (group16_sum(s1 - s0) < 0.0f) ? (cb + 1) : cb;
        s0 = 0.f; s1 = 0.f;
        d = A2.x - xv2.x; s0 = fmaf(d, d, s0);  d = B2.x - xv2.x; s1 = fmaf(d, d, s1);
        d = A2.y - xv2.y; s0 = fmaf(d, d, s0);  d = B2.y - xv2.y; s1 = fmaf(d, d, s1);
        d = A2.z - xv2.z; s0 = fmaf(d, d, s0);  d = B2.z - xv2.z; s1 = fmaf(d, d, s1);
        d = A2.w - xv2.w; s0 = fmaf(d, d, s0);  d = B2.w - xv2.w; s1 = fmaf(d, d, s1);
        cur2 = (group16_sum(s1 - s0) < 0.0f) ? (cc + 1) : cc;
        s0 = 0.f; s1 = 0.f;
        d = A3.x - xv3.x; s0 = fmaf(d, d, s0);  d = B3.x - xv3.x; s1 = fmaf(d, d, s1);
        d = A3.y - xv3.y; s0 = fmaf(d, d, s0);  d = B3.y - xv3.y; s1 = fmaf(d, d, s1);
        d = A3.z - xv3.z; s0 = fmaf(d, d, s0);  d = B3.z - xv3.z; s1 = fmaf(d, d, s1);
        d = A3.w - xv3.w; s0 = fmaf(d, d, s0);  d = B3.w - xv3.w; s1 = fmaf(d, d, s1);
        cur3 = (group16_sum(s1 - s0) < 0.0f) ? (cd + 1) : cd;
    }

    if (q == 0) {
        leaf_out[b * 256 + g]       = (float)cur0;
        leaf_out[b * 256 + 64 + g]  = (float)cur1;
        leaf_out[b * 256 + 128 + g] = (float)cur2;
        leaf_out[b * 256 + 192 + g] = (float)cur3;
        atomicAdd(&cntl[cur0 - 127], 1u);
        atomicAdd(&cntl[cur1 - 127], 1u);
        atomicAdd(&cntl[cur2 - 127], 1u);
        atomicAdd(&cntl[cur3 - 127], 1u);
    }

    // accumulate quads into leaf rows (group (L+q)%8 balanced)
    {
        float* dst = &Sl[(cur0 - 127) * RS + q4];
        atomicAdd(dst + 0, xv0.x); atomicAdd(dst + 1, xv0.y);
        atomicAdd(dst + 2, xv0.z); atomicAdd(dst + 3, xv0.w);
        dst = &Sl[(cur1 - 127) * RS + q4];
        atomicAdd(dst + 0, xv1.x); atomicAdd(dst + 1, xv1.y);
        atomicAdd(dst + 2, xv1.z); atomicAdd(dst + 3, xv1.w);
        dst = &Sl[(cur2 - 127) * RS + q4];
        atomicAdd(dst + 0, xv2.x); atomicAdd(dst + 1, xv2.y);
        atomicAdd(dst + 2, xv2.z); atomicAdd(dst + 3, xv2.w);
        dst = &Sl[(cur3 - 127) * RS + q4];
        atomicAdd(dst + 0, xv3.x); atomicAdd(dst + 1, xv3.y);
        atomicAdd(dst + 2, xv3.z); atomicAdd(dst + 3, xv3.w);
    }
    __syncthreads();

    // flush block sums to global S (skip zeros; lane-distinct addresses; S pre-zeroed)
    for (int i = t; i < NLEAF * 64; i += 1024) {
        const float v = Sl[(i >> 6) * RS + (i & 63)];
        if (v != 0.0f) atomicAdd(&S[i], v);
    }
    if (t < NLEAF && cntl[t] != 0u) atomicAdd(&cnt[t], cntl[t]);
}

// ---------------- K2: node update (254x64x128 contraction) -------------------
__global__ __launch_bounds__(256) void updateK(const float* __restrict__ nodes,
                                               const float* __restrict__ S,
                                               const unsigned* __restrict__ cnt,
                                               float* __restrict__ out)
{
    const int gid = blockIdx.x * 256 + threadIdx.x;
    if (gid >= NUM_NODES * 64) return;
    const int n = gid >> 6, k = gid & 63;
    const float nd = nodes[gid];
    if (n == 0) { out[gid] = nd; return; }

    const int pos = n + 1;                 // 1-based heap index
    const int Ln = 31 - __clz(pos);        // node level, 1..7
    float su = 0.f, sc = 0.f;
    #pragma unroll 8
    for (int L = 0; L < NLEAF; ++L) {
        const int a = (128 + L) >> (7 - Ln);   // leaf's ancestor at level Ln
        const int x = pos ^ a;
        const int state = (x == 0) ? Ln : (Ln - (31 - __clz(x)) - 1);
        const float lr = 0.3f * ((float)(1 << state) * (1.0f / 128.0f));
        su = fmaf(lr, S[L * 64 + k], su);
        sc = fmaf(lr, (float)cnt[L], sc);
    }
    const float invP = 1.0f / 65536.0f;
    out[gid] = nd + su * invP - (sc * invP) * nd;
}

extern "C" void kernel_launch(void* const* d_in, const int* in_sizes, int n_in,
                              void* d_out, int out_size, void* d_ws, size_t ws_size,
                              hipStream_t stream)
{
    const float* img   = (const float*)d_in[0];   // 2048*2048 f32
    const float* nodes = (const float*)d_in[1];   // 255*64 f32

    float* out_nodes = (float*)d_out;                 // 255*64
    float* out_leaf  = out_nodes + NUM_NODES * 64;    // 65536 (leaf index as f32)

    float*    S    = (float*)d_ws;                    // 128*64 f32
    unsigned* cnt  = (unsigned*)(S + NLEAF * 64);     // 128 u32
    float*    sink = (float*)(cnt + NLEAF);           // preload DCE guard (never written)

    preloadK<<<2048, 256, 0, stream>>>(img, nodes, S, cnt, sink);
    fusedK<<<256, 1024, 0, stream>>>(img, nodes, out_leaf, S, cnt);
    updateK<<<64, 256, 0, stream>>>(nodes, S, cnt, out_nodes);
}

// Round 13
// 108.949 us; speedup vs baseline: 1.6346x; 1.0107x over previous
//
#include <hip/hip_runtime.h>

#define IMG_W 2048
#define NUM_NODES 255
#define NLEAF 128
#define DEPTH 7
#define RS 68   // padded LDS row stride (floats); 16B-chunk bank-group = (row+q)%8 -> balanced

// DPP xor-butterfly add over 16-lane groups (VALU pipe). Butterfly partners add
// identical pairs -> all 16 lanes end bit-identical.
template<int CTRL>
__device__ __forceinline__ float dpp_add(float x) {
    int v = __builtin_amdgcn_update_dpp(0, __float_as_int(x), CTRL, 0xF, 0xF, true);
    return x + __int_as_float(v);
}
__device__ __forceinline__ float group16_sum(float x) {
    x = dpp_add<0xB1>(x);   // quad_perm [1,0,3,2]  : xor 1
    x = dpp_add<0x4E>(x);   // quad_perm [2,3,0,1]  : xor 2
    x = dpp_add<0x141>(x);  // row_half_mirror      : xor 7
    x = dpp_add<0x128>(x);  // row_ror:8            : xor 8
    return x;
}

// ---- K1: 4-way interleaved descent (16 lanes/patch) + LDS-atomic accumulate --
// R10 structure (best known: 42.3 us, VGPR 52). Trims: image gather issued
// first (overlaps LDS fill); row-granular skip in the flush.
__global__ __launch_bounds__(1024, 4) void fusedK(const float* __restrict__ img,
                                                  const float* __restrict__ nodes,
                                                  float* __restrict__ leaf_out,
                                                  float* __restrict__ S,
                                                  unsigned* __restrict__ cnt)
{
    __shared__ float nds[NUM_NODES * RS];   // 69360 B
    __shared__ float Sl[NLEAF * RS];        // 34816 B
    __shared__ unsigned cntl[NLEAF];

    const int t = threadIdx.x;
    const int b = blockIdx.x;
    const int g = t >> 4;          // patch-group 0..63
    const int q = t & 15;          // quad within patch (elements 4q..4q+3)
    const int q4 = q * 4;

    // issue the 4 scattered image gathers FIRST so their ~900-cyc cold latency
    // overlaps the LDS zero/fill below (all retire at the barrier's vmcnt drain)
    float4 xv0, xv1, xv2, xv3;
    {
        const int roff = (q >> 1), coff = (q & 1) * 4;
        int p = b * 256 + g;
        xv0 = *(const float4*)(img + (size_t)((p >> 8) * 8 + roff) * IMG_W + (p & 255) * 8 + coff);
        p += 64;
        xv1 = *(const float4*)(img + (size_t)((p >> 8) * 8 + roff) * IMG_W + (p & 255) * 8 + coff);
        p += 64;
        xv2 = *(const float4*)(img + (size_t)((p >> 8) * 8 + roff) * IMG_W + (p & 255) * 8 + coff);
        p += 64;
        xv3 = *(const float4*)(img + (size_t)((p >> 8) * 8 + roff) * IMG_W + (p & 255) * 8 + coff);
    }

    for (int i = t; i < NLEAF * RS; i += 1024) Sl[i] = 0.0f;
    if (t < NLEAF) cntl[t] = 0u;

    // fill node table (padded rows)
    const float4* ng = (const float4*)nodes;
    for (int i = t; i < NUM_NODES * 16; i += 1024) {
        *(float4*)&nds[(i >> 4) * RS + (i & 15) * 4] = ng[i];
    }
    __syncthreads();

    // 4 interleaved descents: one read batch + one wait per level
    int cur0 = 0, cur1 = 0, cur2 = 0, cur3 = 0;
    #pragma unroll
    for (int lvl = 0; lvl < DEPTH; ++lvl) {
        const int ca = 2 * cur0 + 1, cb = 2 * cur1 + 1, cc = 2 * cur2 + 1, cd = 2 * cur3 + 1;
        const float* pa = &nds[ca * RS + q4];
        const float* pb = &nds[cb * RS + q4];
        const float* pc = &nds[cc * RS + q4];
        const float* pd = &nds[cd * RS + q4];
        const float4 A0 = *(const float4*)(pa);
        const float4 B0 = *(const float4*)(pa + RS);
        const float4 A1 = *(const float4*)(pb);
        const float4 B1 = *(const float4*)(pb + RS);
        const float4 A2 = *(const float4*)(pc);
        const float4 B2 = *(const float4*)(pc + RS);
        const float4 A3 = *(const float4*)(pd);
        const float4 B3 = *(const float4*)(pd + RS);

        float d, s0, s1;
        s0 = 0.f; s1 = 0.f;
        d = A0.x - xv0.x; s0 = fmaf(d, d, s0);  d = B0.x - xv0.x; s1 = fmaf(d, d, s1);
        d = A0.y - xv0.y; s0 = fmaf(d, d, s0);  d = B0.y - xv0.y; s1 = fmaf(d, d, s1);
        d = A0.z - xv0.z; s0 = fmaf(d, d, s0);  d = B0.z - xv0.z; s1 = fmaf(d, d, s1);
        d = A0.w - xv0.w; s0 = fmaf(d, d, s0);  d = B0.w - xv0.w; s1 = fmaf(d, d, s1);
        cur0 = (group16_sum(s1 - s0) < 0.0f) ? (ca + 1) : ca;   // d1<d0 picks c1 (strict)
        s0 = 0.f; s1 = 0.f;
        d = A1.x - xv1.x; s0 = fmaf(d, d, s0);  d = B1.x - xv1.x; s1 = fmaf(d, d, s1);
        d = A1.y - xv1.y; s0 = fmaf(d, d, s0);  d = B1.y - xv1.y; s1 = fmaf(d, d, s1);
        d = A1.z - xv1.z; s0 = fmaf(d, d, s0);  d = B1.z - xv1.z; s1 = fmaf(d, d, s1);
        d = A1.w - xv1.w; s0 = fmaf(d, d, s0);  d = B1.w - xv1.w; s1 = fmaf(d, d, s1);
        cur1 = (group16_sum(s1 - s0) < 0.0f) ? (cb + 1) : cb;
        s0 = 0.f; s1 = 0.f;
        d = A2.x - xv2.x; s0 = fmaf(d, d, s0);  d = B2.x - xv2.x; s1 = fmaf(d, d, s1);
        d = A2.y - xv2.y; s0 = fmaf(d, d, s0);  d = B2.y - xv2.y; s1 = fmaf(d, d, s1);
        d = A2.z - xv2.z; s0 = fmaf(d, d, s0);  d = B2.z - xv2.z; s1 = fmaf(d, d, s1);
        d = A2.w - xv2.w; s0 = fmaf(d, d, s0);  d = B2.w - xv2.w; s1 = fmaf(d, d, s1);
        cur2 = (group16_sum(s1 - s0) < 0.0f) ? (cc + 1) : cc;
        s0 = 0.f; s1 = 0.f;
        d = A3.x - xv3.x; s0 = fmaf(d, d, s0);  d = B3.x - xv3.x; s1 = fmaf(d, d, s1);
        d = A3.y - xv3.y; s0 = fmaf(d, d, s0);  d = B3.y - xv3.y; s1 = fmaf(d, d, s1);
        d = A3.z - xv3.z; s0 = fmaf(d, d, s0);  d = B3.z - xv3.z; s1 = fmaf(d, d, s1);
        d = A3.w - xv3.w; s0 = fmaf(d, d, s0);  d = B3.w - xv3.w; s1 = fmaf(d, d, s1);
        cur3 = (group16_sum(s1 - s0) < 0.0f) ? (cd + 1) : cd;
    }

    if (q == 0) {
        leaf_out[b * 256 + g]       = (float)cur0;
        leaf_out[b * 256 + 64 + g]  = (float)cur1;
        leaf_out[b * 256 + 128 + g] = (float)cur2;
        leaf_out[b * 256 + 192 + g] = (float)cur3;
        atomicAdd(&cntl[cur0 - 127], 1u);
        atomicAdd(&cntl[cur1 - 127], 1u);
        atomicAdd(&cntl[cur2 - 127], 1u);
        atomicAdd(&cntl[cur3 - 127], 1u);
    }

    // accumulate quads into leaf rows (group (L+q)%8 balanced)
    {
        float* dst = &Sl[(cur0 - 127) * RS + q4];
        atomicAdd(dst + 0, xv0.x); atomicAdd(dst + 1, xv0.y);
        atomicAdd(dst + 2, xv0.z); atomicAdd(dst + 3, xv0.w);
        dst = &Sl[(cur1 - 127) * RS + q4];
        atomicAdd(dst + 0, xv1.x); atomicAdd(dst + 1, xv1.y);
        atomicAdd(dst + 2, xv1.z); atomicAdd(dst + 3, xv1.w);
        dst = &Sl[(cur2 - 127) * RS + q4];
        atomicAdd(dst + 0, xv2.x); atomicAdd(dst + 1, xv2.y);
        atomicAdd(dst + 2, xv2.z); atomicAdd(dst + 3, xv2.w);
        dst = &Sl[(cur3 - 127) * RS + q4];
        atomicAdd(dst + 0, xv3.x); atomicAdd(dst + 1, xv3.y);
        atomicAdd(dst + 2, xv3.z); atomicAdd(dst + 3, xv3.w);
    }
    __syncthreads();

    // flush block sums to global S. i>>6 is wave-uniform per iteration -> the
    // cntl[row]==0 test is a uniform branch skipping whole empty rows (~37%).
    for (int i = t; i < NLEAF * 64; i += 1024) {
        const int row = i >> 6;
        if (cntl[row] == 0u) continue;         // wave-uniform skip
        const float v = Sl[row * RS + (i & 63)];
        if (v != 0.0f) atomicAdd(&S[i], v);
    }
    if (t < NLEAF && cntl[t] != 0u) atomicAdd(&cnt[t], cntl[t]);
}

// ---------------- K2: node update (254x64x128 contraction) -------------------
__global__ __launch_bounds__(256) void updateK(const float* __restrict__ nodes,
                                               const float* __restrict__ S,
                                               const unsigned* __restrict__ cnt,
                                               float* __restrict__ out)
{
    const int gid = blockIdx.x * 256 + threadIdx.x;
    if (gid >= NUM_NODES * 64) return;
    const int n = gid >> 6, k = gid & 63;
    const float nd = nodes[gid];
    if (n == 0) { out[gid] = nd; return; }

    const int pos = n + 1;                 // 1-based heap index
    const int Ln = 31 - __clz(pos);        // node level, 1..7
    float su = 0.f, sc = 0.f;
    #pragma unroll 8
    for (int L = 0; L < NLEAF; ++L) {
        const int a = (128 + L) >> (7 - Ln);   // leaf's ancestor at level Ln
        const int x = pos ^ a;
        const int state = (x == 0) ? Ln : (Ln - (31 - __clz(x)) - 1);
        const float lr = 0.3f * ((float)(1 << state) * (1.0f / 128.0f));
        su = fmaf(lr, S[L * 64 + k], su);
        sc = fmaf(lr, (float)cnt[L], sc);
    }
    const float invP = 1.0f / 65536.0f;
    out[gid] = nd + su * invP - (sc * invP) * nd;
}

extern "C" void kernel_launch(void* const* d_in, const int* in_sizes, int n_in,
                              void* d_out, int out_size, void* d_ws, size_t ws_size,
                              hipStream_t stream)
{
    const float* img   = (const float*)d_in[0];   // 2048*2048 f32
    const float* nodes = (const float*)d_in[1];   // 255*64 f32

    float* out_nodes = (float*)d_out;                 // 255*64
    float* out_leaf  = out_nodes + NUM_NODES * 64;    // 65536 (leaf index as f32)

    float*    S   = (float*)d_ws;                     // 128*64 f32
    unsigned* cnt = (unsigned*)(S + NLEAF * 64);      // 128 u32

    hipMemsetAsync(d_ws, 0, (NLEAF * 64) * sizeof(float) + NLEAF * sizeof(unsigned), stream);
    fusedK<<<256, 1024, 0, stream>>>(img, nodes, out_leaf, S, cnt);
    updateK<<<64, 256, 0, stream>>>(nodes, S, cnt, out_nodes);
}